// Round 3
// baseline (28104.953 us; speedup 1.0000x reference)
//
#include <hip/hip_runtime.h>
#include <hip/hip_bf16.h>

// MusicVAE forward. B=256, T=128, NC=96, H=512, G=1536, NB=32, CPB=4.
// All inputs f32; ALL OUTPUTS F32 (reference computes in f32).

#define BB   256
#define TT   128
#define NCC  96
#define HDIM 512
#define GG   1536
#define NBB  32
#define CPBB 4

// ---------------------------------------------------------------------------
// Generic fp32 GEMM:  C[M,N] = A[M,K] @ W[N,K]^T + bias
// 64x64 tile, 256 threads, 4x4 per thread. M % 64 == 0, K % 16 == 0. N guarded.
// ---------------------------------------------------------------------------
__global__ __launch_bounds__(256) void gemm_k(
    const float* __restrict__ A, int lda,
    const float* __restrict__ W, int ldw,
    const float* __restrict__ bias,
    float* __restrict__ C, int ldc,
    int N, int K)
{
  __shared__ float As[16][68];
  __shared__ float Bs[16][68];
  const int tid = threadIdx.x;
  const int tx = tid & 15, ty = tid >> 4;
  const int m0 = blockIdx.x * 64, n0 = blockIdx.y * 64;
  float acc[4][4] = {};
  for (int k0 = 0; k0 < K; k0 += 16) {
#pragma unroll
    for (int i = 0; i < 4; ++i) {
      int e = tid + i * 256;
      int r = e >> 4, kk = e & 15;
      As[kk][r] = A[(size_t)(m0 + r) * lda + k0 + kk];
      int n = n0 + r;
      Bs[kk][r] = (n < N) ? W[(size_t)n * ldw + k0 + kk] : 0.f;
    }
    __syncthreads();
#pragma unroll
    for (int kk = 0; kk < 16; ++kk) {
      float4 a = *reinterpret_cast<const float4*>(&As[kk][ty * 4]);
      float4 b = *reinterpret_cast<const float4*>(&Bs[kk][tx * 4]);
      float av[4] = {a.x, a.y, a.z, a.w};
      float bv[4] = {b.x, b.y, b.z, b.w};
#pragma unroll
      for (int i = 0; i < 4; ++i)
#pragma unroll
        for (int j = 0; j < 4; ++j) acc[i][j] += av[i] * bv[j];
    }
    __syncthreads();
  }
#pragma unroll
  for (int i = 0; i < 4; ++i) {
    int m = m0 + ty * 4 + i;
#pragma unroll
    for (int j = 0; j < 4; ++j) {
      int n = n0 + tx * 4 + j;
      if (n < N) C[(size_t)m * ldc + n] = acc[i][j] + (bias ? bias[n] : 0.f);
    }
  }
}

// ---------------------------------------------------------------------------
// Fused GRU step. Each block computes a [32 x 32] tile of h_new, accumulating
// all three gates (r,z,n): gh = h_prev@Whh^T (+bhh),
// gx = x0@W0^T + x1@W1^T (+bih) (+precomputed gx). PyTorch GRU cell semantics.
// hz=1 means h_prev is all-zeros (skip h GEMM, hp=0).
// ---------------------------------------------------------------------------
struct GruDir {
  const float* h_prev; int h_stride; int hz;
  const float* x0; int x0s; const float* W0; int w0ld; int K0;
  const float* x1; int x1s; const float* W1; int w1ld; int K1;
  const float* gx;                    // [rows, G] (stride G) or null
  const float* Whh;                   // [G, H]
  const float* bih;                   // [G] or null (null when folded into gx)
  const float* bhh;                   // [G]
  float* h_out; int ho_stride;
};
struct GruDir2 { GruDir d[2]; };

#define GRU_ACCUM(Xp, XS, Wp, WLD, KLEN, ACC)                                \
  for (int k0 = 0; k0 < (KLEN); k0 += 16) {                                  \
    _Pragma("unroll")                                                        \
    for (int i = 0; i < 2; ++i) {                                            \
      int e = tid + i * 256;                                                 \
      int r = e >> 4, kk = e & 15;                                           \
      Xs[kk][r] = (Xp)[(size_t)(r0 + r) * (XS) + k0 + kk];                   \
    }                                                                        \
    _Pragma("unroll")                                                        \
    for (int i = 0; i < 6; ++i) {                                            \
      int e = tid + i * 256;                                                 \
      int g = e >> 9, rem = e & 511;                                         \
      int c = rem >> 4, kk = rem & 15;                                       \
      Ws[g][kk][c] = (Wp)[(size_t)(g * HDIM + c0 + c) * (WLD) + k0 + kk];    \
    }                                                                        \
    __syncthreads();                                                         \
    _Pragma("unroll")                                                        \
    for (int kk = 0; kk < 16; ++kk) {                                        \
      float2 xv = *reinterpret_cast<const float2*>(&Xs[kk][ty * 2]);         \
      _Pragma("unroll")                                                      \
      for (int g = 0; g < 3; ++g) {                                          \
        float2 wv = *reinterpret_cast<const float2*>(&Ws[g][kk][tx * 2]);    \
        ACC[g][0][0] += xv.x * wv.x; ACC[g][0][1] += xv.x * wv.y;            \
        ACC[g][1][0] += xv.y * wv.x; ACC[g][1][1] += xv.y * wv.y;            \
      }                                                                      \
    }                                                                        \
    __syncthreads();                                                         \
  }

__global__ __launch_bounds__(256) void gru_step_k(GruDir2 pp)
{
  const GruDir p = pp.d[blockIdx.z];
  __shared__ float Xs[16][34];
  __shared__ float Ws[3][16][34];
  const int tid = threadIdx.x;
  const int tx = tid & 15, ty = tid >> 4;
  const int r0 = blockIdx.x * 32, c0 = blockIdx.y * 32;
  float ah[3][2][2] = {};
  float ax[3][2][2] = {};

  if (!p.hz) { GRU_ACCUM(p.h_prev, p.h_stride, p.Whh, HDIM, HDIM, ah) }
  if (p.x0 && p.K0 > 0) { GRU_ACCUM(p.x0, p.x0s, p.W0, p.w0ld, p.K0, ax) }
  if (p.x1 && p.K1 > 0) { GRU_ACCUM(p.x1, p.x1s, p.W1, p.w1ld, p.K1, ax) }

#pragma unroll
  for (int ii = 0; ii < 2; ++ii) {
    int r = r0 + ty * 2 + ii;
#pragma unroll
    for (int jj = 0; jj < 2; ++jj) {
      int c = c0 + tx * 2 + jj;
      float hr = ah[0][ii][jj] + p.bhh[c];
      float hz_ = ah[1][ii][jj] + p.bhh[HDIM + c];
      float hn = ah[2][ii][jj] + p.bhh[2 * HDIM + c];
      float xr = ax[0][ii][jj], xz = ax[1][ii][jj], xn = ax[2][ii][jj];
      if (p.bih) { xr += p.bih[c]; xz += p.bih[HDIM + c]; xn += p.bih[2 * HDIM + c]; }
      if (p.gx) {
        const float* g = p.gx + (size_t)r * GG;
        xr += g[c]; xz += g[HDIM + c]; xn += g[2 * HDIM + c];
      }
      float rg = 1.f / (1.f + expf(-(xr + hr)));
      float zg = 1.f / (1.f + expf(-(xz + hz_)));
      float ng = tanhf(xn + rg * hn);
      float hp = p.hz ? 0.f : p.h_prev[(size_t)r * p.h_stride + c];
      float hv = (1.f - zg) * ng + zg * hp;
      p.h_out[(size_t)r * p.ho_stride + c] = hv;
    }
  }
}

// ---------------------------------------------------------------------------
// Small elementwise kernels (f32 outputs)
// ---------------------------------------------------------------------------
__global__ void gather_hidden_k(const float* __restrict__ y0,
                                const float* __restrict__ h1f,
                                const float* __restrict__ h1b,
                                float* __restrict__ hidden)
{
  int i = blockIdx.x * 256 + threadIdx.x;
  if (i >= BB * 4 * HDIM) return;
  int b = i >> 11, j = i & 2047;
  float v;
  if (j < 512)       v = y0[(size_t)b * TT * 1024 + 127 * 1024 + j];
  else if (j < 1024) v = y0[(size_t)b * TT * 1024 + j];          // t=0, cols 512..1023
  else if (j < 1536) v = h1f[b * 512 + (j - 1024)];
  else               v = h1b[b * 512 + (j - 1536)];
  hidden[i] = v;
}

__global__ void z_k(const float* __restrict__ mu, const float* __restrict__ lv,
                    const float* __restrict__ eps, float* __restrict__ z,
                    float* __restrict__ out_mu, float* __restrict__ out_lv)
{
  int i = blockIdx.x * 256 + threadIdx.x;
  if (i >= BB * HDIM) return;
  float m = mu[i], l = lv[i];
  z[i] = eps[i] * expf(0.5f * l) + m;
  out_mu[i] = m;
  out_lv[i] = l;
}

// chords_r[bar][b][s][c] = in[b][bar*4+s][c]
__global__ void rearrange_k(const float* __restrict__ in, float* __restrict__ outb)
{
  int i = blockIdx.x * 256 + threadIdx.x;
  if (i >= BB * TT * NCC) return;
  int c = i % 96;
  int s = (i / 96) & 3;
  int b = (i / 384) & 255;
  int bar = i / 98304;
  outb[i] = in[(size_t)b * TT * NCC + (size_t)(bar * 4 + s) * NCC + c];
}

// logits_q rows are q = (bar*256+b)*4+s ; write softmax/log_softmax at [b, t=bar*4+s, c]
__global__ void softmax_k(const float* __restrict__ logits,
                          float* __restrict__ out_sm,
                          float* __restrict__ out_lsm)
{
  int q = blockIdx.x;
  int lane = threadIdx.x;           // 64 lanes
  const float* row = logits + (size_t)q * 96;
  float v0 = row[lane];
  float v1 = (lane < 32) ? row[lane + 64] : -1e30f;
  float m = fmaxf(v0, v1);
#pragma unroll
  for (int o = 32; o; o >>= 1) m = fmaxf(m, __shfl_xor(m, o));
  float e0 = expf(v0 - m);
  float e1 = (lane < 32) ? expf(v1 - m) : 0.f;
  float s = e0 + e1;
#pragma unroll
  for (int o = 32; o; o >>= 1) s += __shfl_xor(s, o);
  float inv = 1.f / s;
  float ls = logf(s);
  int bar = q >> 10, b = (q >> 2) & 255, st = q & 3;
  int t = bar * 4 + st;
  size_t base = (size_t)b * TT * 96 + (size_t)t * 96;
  out_sm[base + lane]  = e0 * inv;
  out_lsm[base + lane] = v0 - m - ls;
  if (lane < 32) {
    out_sm[base + lane + 64]  = e1 * inv;
    out_lsm[base + lane + 64] = v1 - m - ls;
  }
}

__global__ void echo_k(const float* __restrict__ in, float* __restrict__ out)
{
  int i = blockIdx.x * 256 + threadIdx.x;
  if (i < BB * TT * NCC) out[i] = in[i];
}

// ---------------------------------------------------------------------------
extern "C" void kernel_launch(void* const* d_in, const int* in_sizes, int n_in,
                              void* d_out, int out_size, void* d_ws, size_t ws_size,
                              hipStream_t stream)
{
  const float* in        = (const float*)d_in[0];
  const float* eps       = (const float*)d_in[2];
  const float* enc0_Wih  = (const float*)d_in[3];
  const float* enc0_Whh  = (const float*)d_in[4];
  const float* enc0_bih  = (const float*)d_in[5];
  const float* enc0_bhh  = (const float*)d_in[6];
  const float* enc1_Wih  = (const float*)d_in[7];
  const float* enc1_Whh  = (const float*)d_in[8];
  const float* enc1_bih  = (const float*)d_in[9];
  const float* enc1_bhh  = (const float*)d_in[10];
  const float* con0_Wih  = (const float*)d_in[11];
  const float* con0_Whh  = (const float*)d_in[12];
  const float* con0_bih  = (const float*)d_in[13];
  const float* con0_bhh  = (const float*)d_in[14];
  const float* con1_Wih  = (const float*)d_in[15];
  const float* con1_Whh  = (const float*)d_in[16];
  const float* con1_bih  = (const float*)d_in[17];
  const float* con1_bhh  = (const float*)d_in[18];
  const float* dec0_Wih  = (const float*)d_in[19];
  const float* dec0_Whh  = (const float*)d_in[20];
  const float* dec0_bih  = (const float*)d_in[21];
  const float* dec0_bhh  = (const float*)d_in[22];
  const float* dec1_Wih  = (const float*)d_in[23];
  const float* dec1_Whh  = (const float*)d_in[24];
  const float* dec1_bih  = (const float*)d_in[25];
  const float* dec1_bhh  = (const float*)d_in[26];
  const float* W_mu      = (const float*)d_in[27];
  const float* b_mu      = (const float*)d_in[28];
  const float* W_lv      = (const float*)d_in[29];
  const float* b_lv      = (const float*)d_in[30];
  const float* W_ci      = (const float*)d_in[31];
  const float* b_ci      = (const float*)d_in[32];
  const float* W_ch      = (const float*)d_in[33];
  const float* b_ch      = (const float*)d_in[34];
  const float* W_out     = (const float*)d_in[35];
  const float* b_out     = (const float*)d_in[36];

  // ---- workspace: 33,554,432 floats = 128 MiB exactly ----------------------
  // Encoder phase: y0 [B,T,1024] occupies the whole slab.
  // Decoder phase (y0 dead after gather): everything below aliases y0.
  float* ws = (float*)d_ws;
  float* y0        = ws;                       // [B,T,1024]   33,554,432
  float* h0c_all   = ws;                       //  4,194,304   [32,256,512]
  float* h1c_all   = ws + 4194304;             //  4,194,304
  float* chords_r  = ws + 8388608;             //  3,145,728   [32,256,4,96]
  float* d0s[2]    = { ws + 11534336, ws + 15728640 };   // [8192,512] each
  float* d1s[2]    = { ws + 19922944, ws + 24117248 };
  float* logits_q  = ws + 28311552;            //  3,145,728   [32768 rows, ldc 384]
  float* mu_f      = ws + 31457280;            //    131,072
  float* lv_f      = ws + 31588352;            //    131,072
  float* zz        = ws + 31719424;            //    131,072
  float* ci        = ws + 31850496;            //     24,576
  float* chv       = ws + 31875072;            //    131,072
  float* gx_c0     = ws + 32006144;            //    393,216  (ends 32,399,360)

  float* outp   = (float*)d_out;
  float* out_sm = outp;
  float* out_ls = outp + 3145728;
  float* out_mu = outp + 6291456;
  float* out_lv = outp + 6422528;
  float* out_ec = outp + 6553600;

  // fp32 scratch inside the echo region of d_out (overwritten by echo_k at end).
  // Echo region: 3,145,728 floats; we use 1,048,576.
  float* fscr = out_ec;
  float* h1f_pp[2] = { fscr,          fscr + 131072 };
  float* h1b_pp[2] = { fscr + 262144, fscr + 393216 };
  float* hidden    = fscr + 524288;            // [256, 2048]

  auto gemm = [&](const float* A, int lda, const float* W, int ldw, const float* bias,
                  float* C, int ldc, int M, int N, int K) {
    dim3 g(M / 64, (N + 63) / 64);
    gemm_k<<<g, 256, 0, stream>>>(A, lda, W, ldw, bias, C, ldc, N, K);
  };
  auto gru2 = [&](const GruDir& a, const GruDir& b, int rows) {
    GruDir2 p; p.d[0] = a; p.d[1] = b;
    gru_step_k<<<dim3(rows / 32, 16, 2), 256, 0, stream>>>(p);
  };
  auto gru1 = [&](const GruDir& a, int rows) {
    GruDir2 p; p.d[0] = a; p.d[1] = a;
    gru_step_k<<<dim3(rows / 32, 16, 1), 256, 0, stream>>>(p);
  };

  // ---------------- encoder layer 0 (bidirectional, fused per step) ----------
  for (int t = 0; t < TT; ++t) {
    int tr = TT - 1 - t;
    GruDir f = {};
    f.hz = (t == 0);
    f.h_prev = y0 + (size_t)(t > 0 ? t - 1 : 0) * 1024; f.h_stride = TT * 1024;
    f.x0 = in + (size_t)t * NCC; f.x0s = TT * NCC; f.W0 = enc0_Wih; f.w0ld = NCC; f.K0 = NCC;
    f.Whh = enc0_Whh; f.bih = enc0_bih; f.bhh = enc0_bhh;
    f.h_out = y0 + (size_t)t * 1024; f.ho_stride = TT * 1024;
    GruDir bd = {};
    bd.hz = (t == 0);
    bd.h_prev = y0 + (size_t)(t > 0 ? tr + 1 : 0) * 1024 + 512; bd.h_stride = TT * 1024;
    bd.x0 = in + (size_t)tr * NCC; bd.x0s = TT * NCC;
    bd.W0 = enc0_Wih + (size_t)GG * NCC; bd.w0ld = NCC; bd.K0 = NCC;
    bd.Whh = enc0_Whh + (size_t)GG * HDIM; bd.bih = enc0_bih + GG; bd.bhh = enc0_bhh + GG;
    bd.h_out = y0 + (size_t)tr * 1024 + 512; bd.ho_stride = TT * 1024;
    gru2(f, bd, BB);
  }

  // ---------------- encoder layer 1 (bidirectional) --------------------------
  for (int t = 0; t < TT; ++t) {
    int tr = TT - 1 - t;
    GruDir f = {};
    f.hz = (t == 0);
    f.h_prev = h1f_pp[(t > 0 ? t - 1 : 0) & 1]; f.h_stride = 512;
    f.x0 = y0 + (size_t)t * 1024; f.x0s = TT * 1024; f.W0 = enc1_Wih; f.w0ld = 1024; f.K0 = 1024;
    f.Whh = enc1_Whh; f.bih = enc1_bih; f.bhh = enc1_bhh;
    f.h_out = h1f_pp[t & 1]; f.ho_stride = 512;
    GruDir bd = {};
    bd.hz = (t == 0);
    bd.h_prev = h1b_pp[(t > 0 ? t - 1 : 0) & 1]; bd.h_stride = 512;
    bd.x0 = y0 + (size_t)tr * 1024; bd.x0s = TT * 1024;
    bd.W0 = enc1_Wih + (size_t)GG * 1024; bd.w0ld = 1024; bd.K0 = 1024;
    bd.Whh = enc1_Whh + (size_t)GG * HDIM; bd.bih = enc1_bih + GG; bd.bhh = enc1_bhh + GG;
    bd.h_out = h1b_pp[t & 1]; bd.ho_stride = 512;
    gru2(f, bd, BB);
  }

  // ---------------- latent (y0 dead after gather) -----------------------------
  gather_hidden_k<<<2048, 256, 0, stream>>>(y0, h1f_pp[1], h1b_pp[1], hidden);
  rearrange_k<<<12288, 256, 0, stream>>>(in, chords_r);
  gemm(hidden, 2048, W_mu, 2048, b_mu, mu_f, 512, BB, 512, 2048);
  gemm(hidden, 2048, W_lv, 2048, b_lv, lv_f, 512, BB, 512, 2048);
  z_k<<<512, 256, 0, stream>>>(mu_f, lv_f, eps, zz, out_mu, out_lv);
  gemm(zz, 512, W_ci, 512, b_ci, ci, 96, BB, 96, 512);
  gemm(zz, 512, W_ch, 512, b_ch, chv, 512, BB, 512, 512);
  gemm(ci, 96, con0_Wih, 96, con0_bih, gx_c0, GG, BB, GG, 96);

  // ---------------- conductor ------------------------------------------------
  for (int bar = 0; bar < NBB; ++bar) {
    GruDir c0 = {};
    c0.h_prev = (bar == 0) ? chv : h0c_all + (size_t)(bar - 1) * BB * HDIM; c0.h_stride = 512;
    c0.gx = gx_c0;                       // bih already folded into gx_c0
    c0.Whh = con0_Whh; c0.bhh = con0_bhh;
    c0.h_out = h0c_all + (size_t)bar * BB * HDIM; c0.ho_stride = 512;
    gru1(c0, BB);
    GruDir c1 = {};
    c1.h_prev = (bar == 0) ? chv : h1c_all + (size_t)(bar - 1) * BB * HDIM; c1.h_stride = 512;
    c1.x0 = h0c_all + (size_t)bar * BB * HDIM; c1.x0s = 512;
    c1.W0 = con1_Wih; c1.w0ld = 512; c1.K0 = 512;
    c1.Whh = con1_Whh; c1.bih = con1_bih; c1.bhh = con1_bhh;
    c1.h_out = h1c_all + (size_t)bar * BB * HDIM; c1.ho_stride = 512;
    gru1(c1, BB);
  }

  // ---------------- decoder: 32 bars batched (8192 rows), 4 steps ------------
  const int R = NBB * BB;               // 8192 rows
  for (int s = 0; s < CPBB; ++s) {
    float* d0c = d0s[s & 1];
    float* d1c = d1s[s & 1];
    GruDir d0 = {};
    d0.h_prev = (s == 0) ? h0c_all : d0s[(s - 1) & 1]; d0.h_stride = 512;
    d0.x0 = h1c_all; d0.x0s = 512; d0.W0 = dec0_Wih; d0.w0ld = 608; d0.K0 = 512;
    d0.x1 = chords_r + (size_t)s * 96; d0.x1s = 384; d0.W1 = dec0_Wih + 512; d0.w1ld = 608; d0.K1 = 96;
    d0.Whh = dec0_Whh; d0.bih = dec0_bih; d0.bhh = dec0_bhh;
    d0.h_out = d0c; d0.ho_stride = 512;
    gru1(d0, R);
    GruDir d1 = {};
    d1.h_prev = (s == 0) ? h1c_all : d1s[(s - 1) & 1]; d1.h_stride = 512;
    d1.x0 = d0c; d1.x0s = 512; d1.W0 = dec1_Wih; d1.w0ld = 512; d1.K0 = 512;
    d1.Whh = dec1_Whh; d1.bih = dec1_bih; d1.bhh = dec1_bhh;
    d1.h_out = d1c; d1.ho_stride = 512;
    gru1(d1, R);
    // logits rows q = rr*4 + s live at logits_q[rr*384 + s*96 + c]
    gemm(d1c, 512, W_out, 512, b_out, logits_q + (size_t)s * 96, 384, R, 96, 512);
  }

  // ---------------- softmax + echo (echo erases fscr scratch) ----------------
  softmax_k<<<NBB * BB * CPBB, 64, 0, stream>>>(logits_q, out_sm, out_ls);
  echo_k<<<12288, 256, 0, stream>>>(in, out_ec);
}

// Round 4
// 17738.120 us; speedup vs baseline: 1.5844x; 1.5844x over previous
//
#include <hip/hip_runtime.h>

// MusicVAE forward. B=256, T=128, NC=96, H=512, G=1536, NB=32, CPB=4.
// All inputs f32; all outputs f32. bf16 MFMA compute, f32 state/accumulate.

#define BB   256
#define TT   128
#define NCC  96
#define HDIM 512
#define GG   1536
#define NBB  32
#define CPBB 4

typedef __attribute__((ext_vector_type(4))) float f32x4;
typedef __attribute__((ext_vector_type(8))) short bf16x8;

__device__ __forceinline__ unsigned short f2b(float x) {
  unsigned int u = __builtin_bit_cast(unsigned int, x);
  u += 0x7fff + ((u >> 16) & 1);
  return (unsigned short)(u >> 16);
}
__device__ __forceinline__ float b2f(unsigned short h) {
  unsigned int u = ((unsigned int)h) << 16;
  return __builtin_bit_cast(float, u);
}

__global__ void cvt_bf16_k(const float* __restrict__ s, unsigned short* __restrict__ d, int n4) {
  int i = blockIdx.x * 256 + threadIdx.x;
  if (i >= n4) return;
  float4 v = reinterpret_cast<const float4*>(s)[i];
  ushort4 o;
  o.x = f2b(v.x); o.y = f2b(v.y); o.z = f2b(v.z); o.w = f2b(v.w);
  reinterpret_cast<ushort4*>(d)[i] = o;
}

// stage 16 f32 -> 16 bf16 into As[arow][ak..ak+15]
__device__ __forceinline__ void stageA_f32(unsigned short (*As)[40], int arow, int ak,
                                           const float* rowp) {
  const float4* s4 = reinterpret_cast<const float4*>(rowp);
  unsigned int pk[8];
#pragma unroll
  for (int q = 0; q < 4; ++q) {
    float4 v = s4[q];
    pk[q * 2]     = (unsigned)f2b(v.x) | ((unsigned)f2b(v.y) << 16);
    pk[q * 2 + 1] = (unsigned)f2b(v.z) | ((unsigned)f2b(v.w) << 16);
  }
  uint4 u0; u0.x = pk[0]; u0.y = pk[1]; u0.z = pk[2]; u0.w = pk[3];
  uint4 u1; u1.x = pk[4]; u1.y = pk[5]; u1.z = pk[6]; u1.w = pk[7];
  *reinterpret_cast<uint4*>(&As[arow][ak])     = u0;
  *reinterpret_cast<uint4*>(&As[arow][ak + 8]) = u1;
}

// ---------------------------------------------------------------------------
// MFMA GRU step. Block: 256 thr = 4 waves; tile 128 rows x 64 cols (of H=512).
// Gates accumulate in 4 banks: R, Z, N_x, N_h (n-gate needs x/h split).
// ---------------------------------------------------------------------------
struct GDir {
  const float* h_prev; int hs; int hz;
  const float* x0f; const unsigned short* x0b; int x0s;
  const unsigned short* W0; int w0ld; int K0;
  const float* x1f; int x1sp; const unsigned short* W1; int w1ld; int K1;
  const float* gx;
  const unsigned short* Whh;
  const float* bih; const float* bhh;
  float* h_out; int os;
  unsigned short* h_out2; int o2s;
};
struct GDir2 { GDir d[2]; };

#define GRU_TAIL(WP, WLD_, NACC)                                               \
    { _Pragma("unroll")                                                        \
      for (int g = 0; g < 3; ++g) {                                            \
        const unsigned short* wsrc = (WP) + (size_t)(g * HDIM + c0 + bn) * (size_t)(WLD_) + k0 + bk; \
        *reinterpret_cast<uint4*>(&Bs[g][bn][bk]) = *reinterpret_cast<const uint4*>(wsrc); \
      } }                                                                      \
    __syncthreads();                                                           \
    { bf16x8 af[4];                                                            \
      _Pragma("unroll")                                                        \
      for (int i = 0; i < 4; ++i)                                              \
        af[i] = *reinterpret_cast<const bf16x8*>(&As[wr * 64 + i * 16 + (lane & 15)][(lane >> 4) * 8]); \
      _Pragma("unroll")                                                        \
      for (int j = 0; j < 2; ++j) {                                            \
        const int bcol = wc * 32 + j * 16 + (lane & 15);                       \
        bf16x8 b0 = *reinterpret_cast<const bf16x8*>(&Bs[0][bcol][(lane >> 4) * 8]); \
        bf16x8 b1 = *reinterpret_cast<const bf16x8*>(&Bs[1][bcol][(lane >> 4) * 8]); \
        bf16x8 b2 = *reinterpret_cast<const bf16x8*>(&Bs[2][bcol][(lane >> 4) * 8]); \
        _Pragma("unroll")                                                      \
        for (int i = 0; i < 4; ++i) {                                          \
          accR[i][j] = __builtin_amdgcn_mfma_f32_16x16x32_bf16(af[i], b0, accR[i][j], 0, 0, 0); \
          accZ[i][j] = __builtin_amdgcn_mfma_f32_16x16x32_bf16(af[i], b1, accZ[i][j], 0, 0, 0); \
          NACC[i][j] = __builtin_amdgcn_mfma_f32_16x16x32_bf16(af[i], b2, NACC[i][j], 0, 0, 0); \
        } } }                                                                  \
    __syncthreads();

#define GRU_PHASE_F32(KLEN, BASE, STRIDE, WP, WLD_, NACC)                      \
  for (int k0 = 0; k0 < (KLEN); k0 += 32) {                                    \
    stageA_f32(As, arow, ak, (BASE) + (size_t)(r0 + arow) * (STRIDE) + k0 + ak); \
    GRU_TAIL(WP, WLD_, NACC)                                                   \
  }

#define GRU_PHASE_BF(KLEN, BASE, STRIDE, WP, WLD_, NACC)                       \
  for (int k0 = 0; k0 < (KLEN); k0 += 32) {                                    \
    { const uint4* s4 = reinterpret_cast<const uint4*>((BASE) + (size_t)(r0 + arow) * (STRIDE) + k0 + ak); \
      *reinterpret_cast<uint4*>(&As[arow][ak])     = s4[0];                    \
      *reinterpret_cast<uint4*>(&As[arow][ak + 8]) = s4[1]; }                  \
    GRU_TAIL(WP, WLD_, NACC)                                                   \
  }

#define GRU_PHASE_CH(KLEN, BASE, SP, WP, WLD_, NACC)                           \
  for (int k0 = 0; k0 < (KLEN); k0 += 32) {                                    \
    { int rr_ = r0 + arow; int bb_ = rr_ & 255, bar_ = rr_ >> 8;               \
      stageA_f32(As, arow, ak, (BASE) + (size_t)bb_ * 12288 + bar_ * 384 + (SP) * 96 + k0 + ak); } \
    GRU_TAIL(WP, WLD_, NACC)                                                   \
  }

__global__ __launch_bounds__(256) void mfma_gru_k(GDir2 pp)
{
  const GDir p = pp.d[blockIdx.z];
  __shared__ unsigned short As[128][40];
  __shared__ unsigned short Bs[3][64][40];
  const int tid = threadIdx.x;
  const int lane = tid & 63, wv = tid >> 6;
  const int wr = wv >> 1, wc = wv & 1;
  const int r0 = blockIdx.x * 128, c0 = blockIdx.y * 64;
  const int arow = tid >> 1, ak = (tid & 1) * 16;
  const int bn = tid >> 2, bk = (tid & 3) * 8;
  f32x4 accR[4][2] = {}, accZ[4][2] = {}, accNX[4][2] = {}, accNH[4][2] = {};

  if (!p.hz) { GRU_PHASE_F32(HDIM, p.h_prev, p.hs, p.Whh, HDIM, accNH) }
  if (p.K0 > 0) {
    if (p.x0b) { GRU_PHASE_BF(p.K0, p.x0b, p.x0s, p.W0, p.w0ld, accNX) }
    else       { GRU_PHASE_F32(p.K0, p.x0f, p.x0s, p.W0, p.w0ld, accNX) }
  }
  if (p.K1 > 0) { GRU_PHASE_CH(p.K1, p.x1f, p.x1sp, p.W1, p.w1ld, accNX) }

#pragma unroll
  for (int i = 0; i < 4; ++i) {
#pragma unroll
    for (int j = 0; j < 2; ++j) {
#pragma unroll
      for (int rg = 0; rg < 4; ++rg) {
        int r = r0 + wr * 64 + i * 16 + ((lane >> 4) << 2) + rg;
        int c = c0 + wc * 32 + j * 16 + (lane & 15);
        float sr = accR[i][j][rg] + p.bhh[c];
        float sz = accZ[i][j][rg] + p.bhh[HDIM + c];
        float nx = accNX[i][j][rg];
        float nh = accNH[i][j][rg] + p.bhh[2 * HDIM + c];
        if (p.bih) { sr += p.bih[c]; sz += p.bih[HDIM + c]; nx += p.bih[2 * HDIM + c]; }
        if (p.gx) {
          const float* gxr = p.gx + (size_t)r * GG;
          sr += gxr[c]; sz += gxr[HDIM + c]; nx += gxr[2 * HDIM + c];
        }
        float rgate = 1.f / (1.f + expf(-sr));
        float zgate = 1.f / (1.f + expf(-sz));
        float ngate = tanhf(nx + rgate * nh);
        float hp = p.hz ? 0.f : p.h_prev[(size_t)r * p.hs + c];
        float hv = (1.f - zgate) * ngate + zgate * hp;
        p.h_out[(size_t)r * p.os + c] = hv;
        if (p.h_out2) p.h_out2[(size_t)r * p.o2s + c] = f2b(hv);
      }
    }
  }
}

// ---------------------------------------------------------------------------
// MFMA GEMM: C[M,N] = A[M,K]@W[N,K]^T + bias. 128x64 tile. M%128==0, K%32==0.
// ---------------------------------------------------------------------------
__global__ __launch_bounds__(256) void mfma_gemm_k(
    const float* __restrict__ A, int lda,
    const float* __restrict__ W, int ldw,
    const float* __restrict__ bias,
    float* __restrict__ C, int ldc, int N, int K)
{
  __shared__ unsigned short As[128][40];
  __shared__ unsigned short Bs[64][40];
  const int tid = threadIdx.x;
  const int lane = tid & 63, wv = tid >> 6;
  const int wr = wv >> 1, wc = wv & 1;
  const int r0 = blockIdx.x * 128, c0 = blockIdx.y * 64;
  const int arow = tid >> 1, ak = (tid & 1) * 16;
  const int bn = tid >> 2, bk = (tid & 3) * 8;
  f32x4 acc[4][2] = {};
  for (int k0 = 0; k0 < K; k0 += 32) {
    stageA_f32(As, arow, ak, A + (size_t)(r0 + arow) * lda + k0 + ak);
    {
      int n = c0 + bn;
      uint4 u;
      if (n < N) {
        const float4* s4 = reinterpret_cast<const float4*>(W + (size_t)n * ldw + k0 + bk);
        float4 v0 = s4[0], v1 = s4[1];
        u.x = (unsigned)f2b(v0.x) | ((unsigned)f2b(v0.y) << 16);
        u.y = (unsigned)f2b(v0.z) | ((unsigned)f2b(v0.w) << 16);
        u.z = (unsigned)f2b(v1.x) | ((unsigned)f2b(v1.y) << 16);
        u.w = (unsigned)f2b(v1.z) | ((unsigned)f2b(v1.w) << 16);
      } else { u.x = u.y = u.z = u.w = 0; }
      *reinterpret_cast<uint4*>(&Bs[bn][bk]) = u;
    }
    __syncthreads();
    bf16x8 af[4];
#pragma unroll
    for (int i = 0; i < 4; ++i)
      af[i] = *reinterpret_cast<const bf16x8*>(&As[wr * 64 + i * 16 + (lane & 15)][(lane >> 4) * 8]);
#pragma unroll
    for (int j = 0; j < 2; ++j) {
      bf16x8 bfr = *reinterpret_cast<const bf16x8*>(&Bs[wc * 32 + j * 16 + (lane & 15)][(lane >> 4) * 8]);
#pragma unroll
      for (int i = 0; i < 4; ++i)
        acc[i][j] = __builtin_amdgcn_mfma_f32_16x16x32_bf16(af[i], bfr, acc[i][j], 0, 0, 0);
    }
    __syncthreads();
  }
#pragma unroll
  for (int i = 0; i < 4; ++i)
#pragma unroll
    for (int j = 0; j < 2; ++j)
#pragma unroll
      for (int rg = 0; rg < 4; ++rg) {
        int r = r0 + wr * 64 + i * 16 + ((lane >> 4) << 2) + rg;
        int c = c0 + wc * 32 + j * 16 + (lane & 15);
        if (c < N) C[(size_t)r * ldc + c] = acc[i][j][rg] + (bias ? bias[c] : 0.f);
      }
}

// ---------------------------------------------------------------------------
// Small elementwise kernels
// ---------------------------------------------------------------------------
__global__ void gather_hidden_k(const unsigned short* __restrict__ y0b,
                                const float* __restrict__ h1f,
                                const float* __restrict__ h1b,
                                float* __restrict__ hidden)
{
  int i = blockIdx.x * 256 + threadIdx.x;
  if (i >= BB * 4 * HDIM) return;
  int b = i >> 11, j = i & 2047;
  float v;
  if (j < 512)       v = b2f(y0b[(size_t)b * 131072 + 127 * 1024 + j]);
  else if (j < 1024) v = b2f(y0b[(size_t)b * 131072 + j]);
  else if (j < 1536) v = h1f[b * 512 + (j - 1024)];
  else               v = h1b[b * 512 + (j - 1536)];
  hidden[i] = v;
}

__global__ void z_k(const float* __restrict__ mu, const float* __restrict__ lv,
                    const float* __restrict__ eps, float* __restrict__ z,
                    float* __restrict__ out_mu, float* __restrict__ out_lv)
{
  int i = blockIdx.x * 256 + threadIdx.x;
  if (i >= BB * HDIM) return;
  float m = mu[i], l = lv[i];
  z[i] = eps[i] * expf(0.5f * l) + m;
  out_mu[i] = m;
  out_lv[i] = l;
}

__global__ void softmax_k(const float* __restrict__ logits,
                          float* __restrict__ out_sm,
                          float* __restrict__ out_lsm)
{
  int q = blockIdx.x;
  int lane = threadIdx.x;
  const float* row = logits + (size_t)q * 96;
  float v0 = row[lane];
  float v1 = (lane < 32) ? row[lane + 64] : -1e30f;
  float m = fmaxf(v0, v1);
#pragma unroll
  for (int o = 32; o; o >>= 1) m = fmaxf(m, __shfl_xor(m, o));
  float e0 = expf(v0 - m);
  float e1 = (lane < 32) ? expf(v1 - m) : 0.f;
  float s = e0 + e1;
#pragma unroll
  for (int o = 32; o; o >>= 1) s += __shfl_xor(s, o);
  float inv = 1.f / s, ls = logf(s);
  int b = (q >> 2) & 255;
  int t = (q >> 10) * 4 + (q & 3);
  size_t base = (size_t)b * TT * 96 + (size_t)t * 96;
  out_sm[base + lane]  = e0 * inv;
  out_lsm[base + lane] = v0 - m - ls;
  if (lane < 32) {
    out_sm[base + lane + 64]  = e1 * inv;
    out_lsm[base + lane + 64] = v1 - m - ls;
  }
}

__global__ void echo_k(const float* __restrict__ in, float* __restrict__ out)
{
  int i = blockIdx.x * 256 + threadIdx.x;
  if (i < BB * TT * NCC) out[i] = in[i];
}

// ---------------------------------------------------------------------------
extern "C" void kernel_launch(void* const* d_in, const int* in_sizes, int n_in,
                              void* d_out, int out_size, void* d_ws, size_t ws_size,
                              hipStream_t stream)
{
  const float* in        = (const float*)d_in[0];
  const float* eps       = (const float*)d_in[2];
  const float* enc0_Wih  = (const float*)d_in[3];
  const float* enc0_Whh  = (const float*)d_in[4];
  const float* enc0_bih  = (const float*)d_in[5];
  const float* enc0_bhh  = (const float*)d_in[6];
  const float* enc1_Wih  = (const float*)d_in[7];
  const float* enc1_Whh  = (const float*)d_in[8];
  const float* enc1_bih  = (const float*)d_in[9];
  const float* enc1_bhh  = (const float*)d_in[10];
  const float* con0_Wih  = (const float*)d_in[11];
  const float* con0_Whh  = (const float*)d_in[12];
  const float* con0_bih  = (const float*)d_in[13];
  const float* con0_bhh  = (const float*)d_in[14];
  const float* con1_Wih  = (const float*)d_in[15];
  const float* con1_Whh  = (const float*)d_in[16];
  const float* con1_bih  = (const float*)d_in[17];
  const float* con1_bhh  = (const float*)d_in[18];
  const float* dec0_Wih  = (const float*)d_in[19];
  const float* dec0_Whh  = (const float*)d_in[20];
  const float* dec0_bih  = (const float*)d_in[21];
  const float* dec0_bhh  = (const float*)d_in[22];
  const float* dec1_Wih  = (const float*)d_in[23];
  const float* dec1_Whh  = (const float*)d_in[24];
  const float* dec1_bih  = (const float*)d_in[25];
  const float* dec1_bhh  = (const float*)d_in[26];
  const float* W_mu      = (const float*)d_in[27];
  const float* b_mu      = (const float*)d_in[28];
  const float* W_lv      = (const float*)d_in[29];
  const float* b_lv      = (const float*)d_in[30];
  const float* W_ci      = (const float*)d_in[31];
  const float* b_ci      = (const float*)d_in[32];
  const float* W_ch      = (const float*)d_in[33];
  const float* b_ch      = (const float*)d_in[34];
  const float* W_out     = (const float*)d_in[35];
  const float* b_out     = (const float*)d_in[36];

  // ---- workspace (float slots; total used 32,858,112 < 33,554,432 = 128 MiB)
  float* ws = (float*)d_ws;
  unsigned short* y0b = (unsigned short*)ws;           // [256][128][1024] bf16 (slots 0..16.78M)
  float* h0c   = ws;                                   // decoder aliases of y0b region
  float* h1c   = ws + 4194304;
  float* d0p[2] = { ws + 8388608,  ws + 12582912 };
  float* d1p[2] = { ws + 16777216, ws + 20971520 };
  float* e0pp  = ws + 25165824;                        // [2 pp][2 dir][256][512]
  float* mu_f  = ws + 25690112;
  float* lv_f  = ws + 25821184;
  float* zz    = ws + 25952256;
  float* ci    = ws + 26083328;
  float* chv   = ws + 26107904;
  float* gx_c0 = ws + 26238976;
  unsigned short* Wb = (unsigned short*)(ws + 26738688);  // 12,238,848 bf16

  // bf16 weight offsets
  unsigned short* wb_e0_Wih = Wb;                 // 2x1536x96
  unsigned short* wb_e0_Whh = Wb + 294912;        // 2x1536x512
  unsigned short* wb_e1_Wih = Wb + 1867776;       // 2x1536x1024
  unsigned short* wb_e1_Whh = Wb + 5013504;       // 2x1536x512
  unsigned short* wb_c0_Whh = Wb + 6586368;
  unsigned short* wb_c1_Wih = Wb + 7372800;
  unsigned short* wb_c1_Whh = Wb + 8159232;
  unsigned short* wb_d0_Wih = Wb + 8945664;       // 1536x608
  unsigned short* wb_d0_Whh = Wb + 9879552;
  unsigned short* wb_d1_Wih = Wb + 10665984;
  unsigned short* wb_d1_Whh = Wb + 11452416;

  float* outp   = (float*)d_out;
  float* out_sm = outp;
  float* out_ls = outp + 3145728;
  float* out_mu = outp + 6291456;
  float* out_lv = outp + 6422528;
  float* out_ec = outp + 6553600;
  // scratch in echo region (dead before echo_k runs)
  float* fscr = out_ec;
  float* h1f_pp[2] = { fscr,          fscr + 131072 };
  float* h1b_pp[2] = { fscr + 262144, fscr + 393216 };
  float* hidden    = fscr + 524288;                    // [256][2048]
  float* logits_q  = out_ec;                           // decoder phase: [8192 rows x 384]

  auto cvt = [&](const float* s, unsigned short* d, int n) {
    cvt_bf16_k<<<(n / 4 + 255) / 256, 256, 0, stream>>>(s, d, n / 4);
  };
  auto gemmM = [&](const float* A, int lda, const float* W, int ldw, const float* bias,
                   float* C, int ldc, int M, int N, int K) {
    mfma_gemm_k<<<dim3(M / 128, (N + 63) / 64), 256, 0, stream>>>(A, lda, W, ldw, bias, C, ldc, N, K);
  };
  auto gruM2 = [&](const GDir& a, const GDir& b, int rows) {
    GDir2 q; q.d[0] = a; q.d[1] = b;
    mfma_gru_k<<<dim3(rows / 128, 8, 2), 256, 0, stream>>>(q);
  };
  auto gruM1 = [&](const GDir& a, int rows) {
    GDir2 q; q.d[0] = a; q.d[1] = a;
    mfma_gru_k<<<dim3(rows / 128, 8, 1), 256, 0, stream>>>(q);
  };

  // ---------------- weight conversion ---------------------------------------
  cvt(enc0_Wih, wb_e0_Wih, 294912);
  cvt(enc0_Whh, wb_e0_Whh, 1572864);
  cvt(enc1_Wih, wb_e1_Wih, 3145728);
  cvt(enc1_Whh, wb_e1_Whh, 1572864);
  cvt(con0_Whh, wb_c0_Whh, 786432);
  cvt(con1_Wih, wb_c1_Wih, 786432);
  cvt(con1_Whh, wb_c1_Whh, 786432);
  cvt(dec0_Wih, wb_d0_Wih, 933888);
  cvt(dec0_Whh, wb_d0_Whh, 786432);
  cvt(dec1_Wih, wb_d1_Wih, 786432);
  cvt(dec1_Whh, wb_d1_Whh, 786432);

  // ---------------- encoder layer 0 ------------------------------------------
  for (int t = 0; t < TT; ++t) {
    int tr = TT - 1 - t;
    GDir f = {};
    f.hz = (t == 0);
    f.h_prev = e0pp + (size_t)((t + 1) & 1) * 262144; f.hs = 512;
    f.x0f = in + (size_t)t * 96; f.x0s = 12288; f.W0 = wb_e0_Wih; f.w0ld = 96; f.K0 = 96;
    f.Whh = wb_e0_Whh; f.bih = enc0_bih; f.bhh = enc0_bhh;
    f.h_out = e0pp + (size_t)(t & 1) * 262144; f.os = 512;
    f.h_out2 = y0b + (size_t)t * 1024; f.o2s = 131072;
    GDir bd = {};
    bd.hz = (t == 0);
    bd.h_prev = e0pp + (size_t)((t + 1) & 1) * 262144 + 131072; bd.hs = 512;
    bd.x0f = in + (size_t)tr * 96; bd.x0s = 12288;
    bd.W0 = wb_e0_Wih + 147456; bd.w0ld = 96; bd.K0 = 96;
    bd.Whh = wb_e0_Whh + 786432; bd.bih = enc0_bih + GG; bd.bhh = enc0_bhh + GG;
    bd.h_out = e0pp + (size_t)(t & 1) * 262144 + 131072; bd.os = 512;
    bd.h_out2 = y0b + (size_t)tr * 1024 + 512; bd.o2s = 131072;
    gruM2(f, bd, BB);
  }

  // ---------------- encoder layer 1 ------------------------------------------
  for (int t = 0; t < TT; ++t) {
    int tr = TT - 1 - t;
    GDir f = {};
    f.hz = (t == 0);
    f.h_prev = h1f_pp[(t + 1) & 1]; f.hs = 512;
    f.x0b = y0b + (size_t)t * 1024; f.x0s = 131072; f.W0 = wb_e1_Wih; f.w0ld = 1024; f.K0 = 1024;
    f.Whh = wb_e1_Whh; f.bih = enc1_bih; f.bhh = enc1_bhh;
    f.h_out = h1f_pp[t & 1]; f.os = 512;
    GDir bd = {};
    bd.hz = (t == 0);
    bd.h_prev = h1b_pp[(t + 1) & 1]; bd.hs = 512;
    bd.x0b = y0b + (size_t)tr * 1024; bd.x0s = 131072;
    bd.W0 = wb_e1_Wih + 1572864; bd.w0ld = 1024; bd.K0 = 1024;
    bd.Whh = wb_e1_Whh + 786432; bd.bih = enc1_bih + GG; bd.bhh = enc1_bhh + GG;
    bd.h_out = h1b_pp[t & 1]; bd.os = 512;
    gruM2(f, bd, BB);
  }

  // ---------------- latent ----------------------------------------------------
  gather_hidden_k<<<2048, 256, 0, stream>>>(y0b, h1f_pp[1], h1b_pp[1], hidden);
  gemmM(hidden, 2048, W_mu, 2048, b_mu, mu_f, 512, BB, 512, 2048);
  gemmM(hidden, 2048, W_lv, 2048, b_lv, lv_f, 512, BB, 512, 2048);
  z_k<<<512, 256, 0, stream>>>(mu_f, lv_f, eps, zz, out_mu, out_lv);
  gemmM(zz, 512, W_ci, 512, b_ci, ci, 96, BB, 96, 512);
  gemmM(zz, 512, W_ch, 512, b_ch, chv, 512, BB, 512, 512);
  gemmM(ci, 96, con0_Wih, 96, con0_bih, gx_c0, GG, BB, GG, 96);

  // ---------------- conductor (y0b dead after gather) -------------------------
  for (int bar = 0; bar < NBB; ++bar) {
    GDir c0 = {};
    c0.h_prev = (bar == 0) ? chv : h0c + (size_t)(bar - 1) * 131072; c0.hs = 512;
    c0.gx = gx_c0;
    c0.Whh = wb_c0_Whh; c0.bhh = con0_bhh;
    c0.h_out = h0c + (size_t)bar * 131072; c0.os = 512;
    gruM1(c0, BB);
    GDir c1 = {};
    c1.h_prev = (bar == 0) ? chv : h1c + (size_t)(bar - 1) * 131072; c1.hs = 512;
    c1.x0f = h0c + (size_t)bar * 131072; c1.x0s = 512;
    c1.W0 = wb_c1_Wih; c1.w0ld = 512; c1.K0 = 512;
    c1.Whh = wb_c1_Whh; c1.bih = con1_bih; c1.bhh = con1_bhh;
    c1.h_out = h1c + (size_t)bar * 131072; c1.os = 512;
    gruM1(c1, BB);
  }

  // ---------------- decoder: 8192 rows, 4 steps -------------------------------
  const int R = NBB * BB;
  for (int s = 0; s < CPBB; ++s) {
    GDir d0 = {};
    d0.h_prev = (s == 0) ? h0c : d0p[(s - 1) & 1]; d0.hs = 512;
    d0.x0f = h1c; d0.x0s = 512; d0.W0 = wb_d0_Wih; d0.w0ld = 608; d0.K0 = 512;
    d0.x1f = in; d0.x1sp = s; d0.W1 = wb_d0_Wih + 512; d0.w1ld = 608; d0.K1 = 96;
    d0.Whh = wb_d0_Whh; d0.bih = dec0_bih; d0.bhh = dec0_bhh;
    d0.h_out = d0p[s & 1]; d0.os = 512;
    gruM1(d0, R);
    GDir d1 = {};
    d1.h_prev = (s == 0) ? h1c : d1p[(s - 1) & 1]; d1.hs = 512;
    d1.x0f = d0p[s & 1]; d1.x0s = 512; d1.W0 = wb_d1_Wih; d1.w0ld = 512; d1.K0 = 512;
    d1.Whh = wb_d1_Whh; d1.bih = dec1_bih; d1.bhh = dec1_bhh;
    d1.h_out = d1p[s & 1]; d1.os = 512;
    gruM1(d1, R);
    gemmM(d1p[s & 1], 512, W_out, 512, b_out, logits_q + (size_t)s * 96, 384, R, 96, 512);
  }

  // ---------------- softmax + echo --------------------------------------------
  softmax_k<<<NBB * BB * CPBB, 64, 0, stream>>>(logits_q, out_sm, out_ls);
  echo_k<<<12288, 256, 0, stream>>>(in, out_ec);
}

// Round 5
// 6776.187 us; speedup vs baseline: 4.1476x; 2.6177x over previous
//
#include <hip/hip_runtime.h>

// MusicVAE forward. B=256, T=128, NC=96, H=512, G=1536, NB=32, CPB=4.
// All inputs f32; all outputs f32. bf16 MFMA compute, f32 state/accumulate.

#define BB   256
#define TT   128
#define NCC  96
#define HDIM 512
#define GG   1536
#define NBB  32
#define CPBB 4

typedef __attribute__((ext_vector_type(4))) float f32x4;
typedef __attribute__((ext_vector_type(8))) short bf16x8;

__device__ __forceinline__ unsigned short f2b(float x) {
  unsigned int u = __builtin_bit_cast(unsigned int, x);
  u += 0x7fff + ((u >> 16) & 1);
  return (unsigned short)(u >> 16);
}
__device__ __forceinline__ float b2f(unsigned short h) {
  unsigned int u = ((unsigned int)h) << 16;
  return __builtin_bit_cast(float, u);
}
__device__ __forceinline__ uint2 packA(float4 v) {
  uint2 r;
  r.x = (unsigned)f2b(v.x) | ((unsigned)f2b(v.y) << 16);
  r.y = (unsigned)f2b(v.z) | ((unsigned)f2b(v.w) << 16);
  return r;
}

__global__ void cvt_bf16_k(const float* __restrict__ s, unsigned short* __restrict__ d, int n4) {
  int i = blockIdx.x * 256 + threadIdx.x;
  if (i >= n4) return;
  float4 v = reinterpret_cast<const float4*>(s)[i];
  ushort4 o;
  o.x = f2b(v.x); o.y = f2b(v.y); o.z = f2b(v.z); o.w = f2b(v.w);
  reinterpret_cast<ushort4*>(d)[i] = o;
}

// ---------------------------------------------------------------------------
// GRU step kernel. Tile 32 rows x 64 cols, 256 thr (4 waves 2x2: 16r x 32c).
// Banks: R, Z (x+h combined), NX (x only), NH (h only). Prefetched k-loop.
// ---------------------------------------------------------------------------
struct GruP {
  const float* h_prev; int hs; int hz;
  const unsigned short* Whh;                 // [3H,H] bf16
  const float* x0f; const unsigned short* x0b; int x0s;
  const unsigned short* W0; int w0ld; int K0;
  const float* x1f; int x1sp; const unsigned short* W1; int w1ld; int K1;
  const float* gxf;                          // f32 gx stride G (bih folded)
  const unsigned short* gxb; int gxros;      // bf16 gx [.,1536] (bih folded)
  const float* bih; const float* bhh;
  float* h_out; int os;
  unsigned short* h_out2; int o2s;
};
struct GruP2 { GruP d[2]; };

#define LB3(WP, WLD_, G_, KOFF) \
  (*reinterpret_cast<const uint4*>((WP) + (size_t)((G_) * HDIM + c0 + bn) * (size_t)(WLD_) + (KOFF) + bk))

#define AL_H(KOFF, DST)  DST = packA(*reinterpret_cast<const float4*>(p.h_prev + (size_t)(r0 + arow) * p.hs + (KOFF) + ak));
#define AL_X0F(KOFF, DST) DST = packA(*reinterpret_cast<const float4*>(p.x0f + (size_t)(r0 + arow) * p.x0s + (KOFF) + ak));
#define AL_X0B(KOFF, DST) DST = *reinterpret_cast<const uint2*>(p.x0b + (size_t)(r0 + arow) * p.x0s + (KOFF) + ak);
#define AL_CH(KOFF, DST) { int rr_ = r0 + arow; \
  DST = packA(*reinterpret_cast<const float4*>(p.x1f + (size_t)(rr_ & 255) * 12288 + (rr_ >> 8) * 384 + p.x1sp * 96 + (KOFF) + ak)); }

#define GRU_PHASE(KLEN, ALOAD, WP, WLD_, ACCN)                                 \
  { uint2 aC; uint4 b0c, b1c, b2c;                                             \
    ALOAD(0, aC)                                                               \
    b0c = LB3(WP, WLD_, 0, 0); b1c = LB3(WP, WLD_, 1, 0); b2c = LB3(WP, WLD_, 2, 0); \
    for (int k0 = 0; k0 < (KLEN); k0 += 32) {                                  \
      __syncthreads();                                                         \
      *reinterpret_cast<uint2*>(&As[arow][ak]) = aC;                           \
      *reinterpret_cast<uint4*>(&Bs[0][bn][bk]) = b0c;                         \
      *reinterpret_cast<uint4*>(&Bs[1][bn][bk]) = b1c;                         \
      *reinterpret_cast<uint4*>(&Bs[2][bn][bk]) = b2c;                         \
      if (k0 + 32 < (KLEN)) {                                                  \
        ALOAD(k0 + 32, aC)                                                     \
        b0c = LB3(WP, WLD_, 0, k0 + 32); b1c = LB3(WP, WLD_, 1, k0 + 32); b2c = LB3(WP, WLD_, 2, k0 + 32); \
      }                                                                        \
      __syncthreads();                                                         \
      bf16x8 afr = *reinterpret_cast<const bf16x8*>(&As[wr * 16 + (lane & 15)][(lane >> 4) * 8]); \
      _Pragma("unroll")                                                        \
      for (int j = 0; j < 2; ++j) {                                            \
        const int bc = wc * 32 + j * 16 + (lane & 15);                         \
        bf16x8 f0 = *reinterpret_cast<const bf16x8*>(&Bs[0][bc][(lane >> 4) * 8]); \
        bf16x8 f1 = *reinterpret_cast<const bf16x8*>(&Bs[1][bc][(lane >> 4) * 8]); \
        bf16x8 f2 = *reinterpret_cast<const bf16x8*>(&Bs[2][bc][(lane >> 4) * 8]); \
        aR[j] = __builtin_amdgcn_mfma_f32_16x16x32_bf16(afr, f0, aR[j], 0, 0, 0); \
        aZ[j] = __builtin_amdgcn_mfma_f32_16x16x32_bf16(afr, f1, aZ[j], 0, 0, 0); \
        ACCN[j] = __builtin_amdgcn_mfma_f32_16x16x32_bf16(afr, f2, ACCN[j], 0, 0, 0); \
      }                                                                        \
    } }

__global__ __launch_bounds__(256) void gru_k(GruP2 pp)
{
  const GruP p = pp.d[blockIdx.z];
  __shared__ unsigned short As[32][40];
  __shared__ unsigned short Bs[3][64][40];
  const int tid = threadIdx.x;
  const int lane = tid & 63, wv = tid >> 6;
  const int wr = wv >> 1, wc = wv & 1;
  const int r0 = blockIdx.x * 32, c0 = blockIdx.y * 64;
  const int arow = tid >> 3, ak = (tid & 7) * 4;
  const int bn = tid >> 2, bk = (tid & 3) * 8;
  f32x4 aR[2] = {}, aZ[2] = {}, aNX[2] = {}, aNH[2] = {};

  if (!p.hz) { GRU_PHASE(HDIM, AL_H, p.Whh, HDIM, aNH) }
  if (p.K0 > 0) {
    if (p.x0b) { GRU_PHASE(p.K0, AL_X0B, p.W0, p.w0ld, aNX) }
    else       { GRU_PHASE(p.K0, AL_X0F, p.W0, p.w0ld, aNX) }
  }
  if (p.K1 > 0) { GRU_PHASE(p.K1, AL_CH, p.W1, p.w1ld, aNX) }

#pragma unroll
  for (int j = 0; j < 2; ++j) {
#pragma unroll
    for (int rg = 0; rg < 4; ++rg) {
      int r = r0 + wr * 16 + ((lane >> 4) << 2) + rg;
      int c = c0 + wc * 32 + j * 16 + (lane & 15);
      float sr = aR[j][rg] + p.bhh[c];
      float sz = aZ[j][rg] + p.bhh[HDIM + c];
      float nx = aNX[j][rg];
      float nh = aNH[j][rg] + p.bhh[2 * HDIM + c];
      if (p.bih) { sr += p.bih[c]; sz += p.bih[HDIM + c]; nx += p.bih[2 * HDIM + c]; }
      if (p.gxf) {
        const float* g = p.gxf + (size_t)r * GG;
        sr += g[c]; sz += g[HDIM + c]; nx += g[2 * HDIM + c];
      }
      if (p.gxb) {
        const unsigned short* g = p.gxb + (size_t)(p.gxros + r) * 1536;
        sr += b2f(g[c]); sz += b2f(g[HDIM + c]); nx += b2f(g[2 * HDIM + c]);
      }
      float rgate = 1.f / (1.f + expf(-sr));
      float zgate = 1.f / (1.f + expf(-sz));
      float ngate = tanhf(nx + rgate * nh);
      float hp = p.hz ? 0.f : p.h_prev[(size_t)r * p.hs + c];
      float hv = (1.f - zgate) * ngate + zgate * hp;
      p.h_out[(size_t)r * p.os + c] = hv;
      if (p.h_out2) p.h_out2[(size_t)r * p.o2s + c] = f2b(hv);
    }
  }
}

// ---------------------------------------------------------------------------
// GEMM (f32 A, f32 W cvt on the fly, f32 C + bias). Tile 32x64, prefetched.
// ---------------------------------------------------------------------------
__global__ __launch_bounds__(256) void mfma_gemm_k(
    const float* __restrict__ A, int lda,
    const float* __restrict__ W, int ldw,
    const float* __restrict__ bias,
    float* __restrict__ C, int ldc, int N, int K)
{
  __shared__ unsigned short As[32][40];
  __shared__ unsigned short Bs[64][40];
  const int tid = threadIdx.x;
  const int lane = tid & 63, wv = tid >> 6;
  const int wr = wv >> 1, wc = wv & 1;
  const int r0 = blockIdx.x * 32, c0 = blockIdx.y * 64;
  const int arow = tid >> 3, ak = (tid & 7) * 4;
  const int bn = tid >> 2, bk = (tid & 3) * 8;
  f32x4 acc[2] = {};
  const int nOk = (c0 + bn) < N;
  const float* wrow = W + (size_t)(nOk ? (c0 + bn) : 0) * ldw;

  uint2 aC = packA(*reinterpret_cast<const float4*>(A + (size_t)(r0 + arow) * lda + ak));
  uint4 bC;
  {
    float4 v0 = *reinterpret_cast<const float4*>(wrow + bk);
    float4 v1 = *reinterpret_cast<const float4*>(wrow + bk + 4);
    uint2 p0 = packA(v0), p1 = packA(v1);
    bC.x = p0.x; bC.y = p0.y; bC.z = p1.x; bC.w = p1.y;
  }
  for (int k0 = 0; k0 < K; k0 += 32) {
    __syncthreads();
    *reinterpret_cast<uint2*>(&As[arow][ak]) = aC;
    if (nOk) *reinterpret_cast<uint4*>(&Bs[bn][bk]) = bC;
    else { uint4 z; z.x = z.y = z.z = z.w = 0; *reinterpret_cast<uint4*>(&Bs[bn][bk]) = z; }
    if (k0 + 32 < K) {
      aC = packA(*reinterpret_cast<const float4*>(A + (size_t)(r0 + arow) * lda + k0 + 32 + ak));
      float4 v0 = *reinterpret_cast<const float4*>(wrow + k0 + 32 + bk);
      float4 v1 = *reinterpret_cast<const float4*>(wrow + k0 + 32 + bk + 4);
      uint2 p0 = packA(v0), p1 = packA(v1);
      bC.x = p0.x; bC.y = p0.y; bC.z = p1.x; bC.w = p1.y;
    }
    __syncthreads();
    bf16x8 afr = *reinterpret_cast<const bf16x8*>(&As[wr * 16 + (lane & 15)][(lane >> 4) * 8]);
#pragma unroll
    for (int j = 0; j < 2; ++j) {
      bf16x8 bfr = *reinterpret_cast<const bf16x8*>(&Bs[wc * 32 + j * 16 + (lane & 15)][(lane >> 4) * 8]);
      acc[j] = __builtin_amdgcn_mfma_f32_16x16x32_bf16(afr, bfr, acc[j], 0, 0, 0);
    }
    __syncthreads();
  }
#pragma unroll
  for (int j = 0; j < 2; ++j)
#pragma unroll
    for (int rg = 0; rg < 4; ++rg) {
      int r = r0 + wr * 16 + ((lane >> 4) << 2) + rg;
      int c = c0 + wc * 32 + j * 16 + (lane & 15);
      if (c < N) C[(size_t)r * ldc + c] = acc[j][rg] + (bias ? bias[c] : 0.f);
    }
}

// ---------------------------------------------------------------------------
// Chunk GEMM: gx = y0b(b,t) @ W^T + bias -> bf16. A bf16 with (b,t) rows.
// M=4096 (16 t x 256 b), N=1536, K=1024. Tile 32x64, prefetched.
// ---------------------------------------------------------------------------
__global__ __launch_bounds__(256) void gemm_chunk_k(
    const unsigned short* __restrict__ A, int tstep,
    const unsigned short* __restrict__ W,
    const float* __restrict__ bias,
    unsigned short* __restrict__ C)
{
  __shared__ unsigned short As[32][40];
  __shared__ unsigned short Bs[64][40];
  const int tid = threadIdx.x;
  const int lane = tid & 63, wv = tid >> 6;
  const int wr = wv >> 1, wc = wv & 1;
  const int r0 = blockIdx.x * 32, c0 = blockIdx.y * 64;
  const int arow = tid >> 3, ak = (tid & 7) * 4;
  const int bn = tid >> 2, bk = (tid & 3) * 8;
  f32x4 acc[2] = {};
  const int rr = r0 + arow;
  const unsigned short* arowp = A + (long)(rr & 255) * 131072 + (long)(rr >> 8) * tstep;
  const unsigned short* wrow = W + (size_t)(c0 + bn) * 1024;

  uint2 aC = *reinterpret_cast<const uint2*>(arowp + ak);
  uint4 bC = *reinterpret_cast<const uint4*>(wrow + bk);
  for (int k0 = 0; k0 < 1024; k0 += 32) {
    __syncthreads();
    *reinterpret_cast<uint2*>(&As[arow][ak]) = aC;
    *reinterpret_cast<uint4*>(&Bs[bn][bk]) = bC;
    if (k0 + 32 < 1024) {
      aC = *reinterpret_cast<const uint2*>(arowp + k0 + 32 + ak);
      bC = *reinterpret_cast<const uint4*>(wrow + k0 + 32 + bk);
    }
    __syncthreads();
    bf16x8 afr = *reinterpret_cast<const bf16x8*>(&As[wr * 16 + (lane & 15)][(lane >> 4) * 8]);
#pragma unroll
    for (int j = 0; j < 2; ++j) {
      bf16x8 bfr = *reinterpret_cast<const bf16x8*>(&Bs[wc * 32 + j * 16 + (lane & 15)][(lane >> 4) * 8]);
      acc[j] = __builtin_amdgcn_mfma_f32_16x16x32_bf16(afr, bfr, acc[j], 0, 0, 0);
    }
    __syncthreads();
  }
#pragma unroll
  for (int j = 0; j < 2; ++j)
#pragma unroll
    for (int rg = 0; rg < 4; ++rg) {
      int r = r0 + wr * 16 + ((lane >> 4) << 2) + rg;
      int c = c0 + wc * 32 + j * 16 + (lane & 15);
      C[(size_t)r * 1536 + c] = f2b(acc[j][rg] + bias[c]);
    }
}

// ---------------------------------------------------------------------------
// Small elementwise kernels
// ---------------------------------------------------------------------------
__global__ void gather_hidden_k(const unsigned short* __restrict__ y0b,
                                const float* __restrict__ h1f,
                                const float* __restrict__ h1b,
                                float* __restrict__ hidden)
{
  int i = blockIdx.x * 256 + threadIdx.x;
  if (i >= BB * 4 * HDIM) return;
  int b = i >> 11, j = i & 2047;
  float v;
  if (j < 512)       v = b2f(y0b[(size_t)b * 131072 + 127 * 1024 + j]);
  else if (j < 1024) v = b2f(y0b[(size_t)b * 131072 + j]);
  else if (j < 1536) v = h1f[b * 512 + (j - 1024)];
  else               v = h1b[b * 512 + (j - 1536)];
  hidden[i] = v;
}

__global__ void z_k(const float* __restrict__ mu, const float* __restrict__ lv,
                    const float* __restrict__ eps, float* __restrict__ z,
                    float* __restrict__ out_mu, float* __restrict__ out_lv)
{
  int i = blockIdx.x * 256 + threadIdx.x;
  if (i >= BB * HDIM) return;
  float m = mu[i], l = lv[i];
  z[i] = eps[i] * expf(0.5f * l) + m;
  out_mu[i] = m;
  out_lv[i] = l;
}

__global__ void softmax_k(const float* __restrict__ logits,
                          float* __restrict__ out_sm,
                          float* __restrict__ out_lsm)
{
  int q = blockIdx.x;
  int lane = threadIdx.x;
  const float* row = logits + (size_t)q * 96;
  float v0 = row[lane];
  float v1 = (lane < 32) ? row[lane + 64] : -1e30f;
  float m = fmaxf(v0, v1);
#pragma unroll
  for (int o = 32; o; o >>= 1) m = fmaxf(m, __shfl_xor(m, o));
  float e0 = expf(v0 - m);
  float e1 = (lane < 32) ? expf(v1 - m) : 0.f;
  float s = e0 + e1;
#pragma unroll
  for (int o = 32; o; o >>= 1) s += __shfl_xor(s, o);
  float inv = 1.f / s, ls = logf(s);
  int b = (q >> 2) & 255;
  int t = (q >> 10) * 4 + (q & 3);
  size_t base = (size_t)b * TT * 96 + (size_t)t * 96;
  out_sm[base + lane]  = e0 * inv;
  out_lsm[base + lane] = v0 - m - ls;
  if (lane < 32) {
    out_sm[base + lane + 64]  = e1 * inv;
    out_lsm[base + lane + 64] = v1 - m - ls;
  }
}

__global__ void echo_k(const float* __restrict__ in, float* __restrict__ out)
{
  int i = blockIdx.x * 256 + threadIdx.x;
  if (i < BB * TT * NCC) out[i] = in[i];
}

// ---------------------------------------------------------------------------
extern "C" void kernel_launch(void* const* d_in, const int* in_sizes, int n_in,
                              void* d_out, int out_size, void* d_ws, size_t ws_size,
                              hipStream_t stream)
{
  const float* in        = (const float*)d_in[0];
  const float* eps       = (const float*)d_in[2];
  const float* enc0_Wih  = (const float*)d_in[3];
  const float* enc0_Whh  = (const float*)d_in[4];
  const float* enc0_bih  = (const float*)d_in[5];
  const float* enc0_bhh  = (const float*)d_in[6];
  const float* enc1_Wih  = (const float*)d_in[7];
  const float* enc1_Whh  = (const float*)d_in[8];
  const float* enc1_bih  = (const float*)d_in[9];
  const float* enc1_bhh  = (const float*)d_in[10];
  const float* con0_Wih  = (const float*)d_in[11];
  const float* con0_Whh  = (const float*)d_in[12];
  const float* con0_bih  = (const float*)d_in[13];
  const float* con0_bhh  = (const float*)d_in[14];
  const float* con1_Wih  = (const float*)d_in[15];
  const float* con1_Whh  = (const float*)d_in[16];
  const float* con1_bih  = (const float*)d_in[17];
  const float* con1_bhh  = (const float*)d_in[18];
  const float* dec0_Wih  = (const float*)d_in[19];
  const float* dec0_Whh  = (const float*)d_in[20];
  const float* dec0_bih  = (const float*)d_in[21];
  const float* dec0_bhh  = (const float*)d_in[22];
  const float* dec1_Wih  = (const float*)d_in[23];
  const float* dec1_Whh  = (const float*)d_in[24];
  const float* dec1_bih  = (const float*)d_in[25];
  const float* dec1_bhh  = (const float*)d_in[26];
  const float* W_mu      = (const float*)d_in[27];
  const float* b_mu      = (const float*)d_in[28];
  const float* W_lv      = (const float*)d_in[29];
  const float* b_lv      = (const float*)d_in[30];
  const float* W_ci      = (const float*)d_in[31];
  const float* b_ci      = (const float*)d_in[32];
  const float* W_ch      = (const float*)d_in[33];
  const float* b_ch      = (const float*)d_in[34];
  const float* W_out     = (const float*)d_in[35];
  const float* b_out     = (const float*)d_in[36];

  // ---- workspace layout (f32 slots; total 33,554,432 = 128 MiB) -------------
  float* ws = (float*)d_ws;
  unsigned short* y0b = (unsigned short*)ws;            // [256][128][1024] bf16
  float* e0pp   = ws + 16777216;                        // 2 x [2dir][256][512]
  unsigned short* gxF = (unsigned short*)(ws + 17301504);  // [4096][1536] bf16
  unsigned short* gxB = (unsigned short*)(ws + 20447232);
  // decoder-phase aliases (y0b/gx dead):
  float* h0c   = ws;                                    // [32*256, 512]
  float* h1c   = ws + 4194304;
  float* d0p[2] = { ws + 8388608,  ws + 12582912 };
  float* d1p[2] = { ws + 16777216, ws + 20971520 };
  // persistent smalls
  float* mu_f  = ws + 25165824;
  float* lv_f  = ws + 25296896;
  float* zz    = ws + 25427968;
  float* ci    = ws + 25559040;
  float* chv   = ws + 25583616;
  float* gx_c0 = ws + 25714688;                         // ends 26,107,904
  unsigned short* Wb = (unsigned short*)(ws + 27435008);   // 12,238,848 bf16

  unsigned short* wb_e0_Wih = Wb;                 // 2x1536x96
  unsigned short* wb_e0_Whh = Wb + 294912;        // 2x1536x512
  unsigned short* wb_e1_Wih = Wb + 1867776;       // 2x1536x1024
  unsigned short* wb_e1_Whh = Wb + 5013504;       // 2x1536x512
  unsigned short* wb_c0_Whh = Wb + 6586368;
  unsigned short* wb_c1_Wih = Wb + 7372800;
  unsigned short* wb_c1_Whh = Wb + 8159232;
  unsigned short* wb_d0_Wih = Wb + 8945664;       // 1536x608
  unsigned short* wb_d0_Whh = Wb + 9879552;
  unsigned short* wb_d1_Wih = Wb + 10665984;
  unsigned short* wb_d1_Whh = Wb + 11452416;

  float* outp   = (float*)d_out;
  float* out_sm = outp;
  float* out_ls = outp + 3145728;
  float* out_mu = outp + 6291456;
  float* out_lv = outp + 6422528;
  float* out_ec = outp + 6553600;
  // scratch in echo region (dead before echo_k)
  float* fscr = out_ec;
  float* h1f_pp[2] = { fscr,          fscr + 131072 };
  float* h1b_pp[2] = { fscr + 262144, fscr + 393216 };
  float* hidden    = fscr + 524288;                    // [256][2048]
  float* logits_q  = out_ec;                           // decoder: [8192 x 384]

  auto cvt = [&](const float* s, unsigned short* d, int n) {
    cvt_bf16_k<<<(n / 4 + 255) / 256, 256, 0, stream>>>(s, d, n / 4);
  };
  auto gemmM = [&](const float* A, int lda, const float* W, int ldw, const float* bias,
                   float* C, int ldc, int M, int N, int K) {
    mfma_gemm_k<<<dim3(M / 32, (N + 63) / 64), 256, 0, stream>>>(A, lda, W, ldw, bias, C, ldc, N, K);
  };
  auto gru2 = [&](const GruP& a, const GruP& b, int rows) {
    GruP2 q; q.d[0] = a; q.d[1] = b;
    gru_k<<<dim3(rows / 32, 8, 2), 256, 0, stream>>>(q);
  };
  auto gru1 = [&](const GruP& a, int rows) {
    GruP2 q; q.d[0] = a; q.d[1] = a;
    gru_k<<<dim3(rows / 32, 8, 1), 256, 0, stream>>>(q);
  };

  // ---------------- weight conversion ---------------------------------------
  cvt(enc0_Wih, wb_e0_Wih, 294912);
  cvt(enc0_Whh, wb_e0_Whh, 1572864);
  cvt(enc1_Wih, wb_e1_Wih, 3145728);
  cvt(enc1_Whh, wb_e1_Whh, 1572864);
  cvt(con0_Whh, wb_c0_Whh, 786432);
  cvt(con1_Wih, wb_c1_Wih, 786432);
  cvt(con1_Whh, wb_c1_Whh, 786432);
  cvt(dec0_Wih, wb_d0_Wih, 933888);
  cvt(dec0_Whh, wb_d0_Whh, 786432);
  cvt(dec1_Wih, wb_d1_Wih, 786432);
  cvt(dec1_Whh, wb_d1_Whh, 786432);

  // ---------------- encoder layer 0 ------------------------------------------
  for (int t = 0; t < TT; ++t) {
    int tr = TT - 1 - t;
    GruP f = {};
    f.hz = (t == 0);
    f.h_prev = e0pp + (size_t)((t + 1) & 1) * 262144; f.hs = 512;
    f.x0f = in + (size_t)t * 96; f.x0s = 12288; f.W0 = wb_e0_Wih; f.w0ld = 96; f.K0 = 96;
    f.Whh = wb_e0_Whh; f.bih = enc0_bih; f.bhh = enc0_bhh;
    f.h_out = e0pp + (size_t)(t & 1) * 262144; f.os = 512;
    f.h_out2 = y0b + (size_t)t * 1024; f.o2s = 131072;
    GruP bd = {};
    bd.hz = (t == 0);
    bd.h_prev = e0pp + (size_t)((t + 1) & 1) * 262144 + 131072; bd.hs = 512;
    bd.x0f = in + (size_t)tr * 96; bd.x0s = 12288;
    bd.W0 = wb_e0_Wih + 147456; bd.w0ld = 96; bd.K0 = 96;
    bd.Whh = wb_e0_Whh + 786432; bd.bih = enc0_bih + GG; bd.bhh = enc0_bhh + GG;
    bd.h_out = e0pp + (size_t)(t & 1) * 262144 + 131072; bd.os = 512;
    bd.h_out2 = y0b + (size_t)tr * 1024 + 512; bd.o2s = 131072;
    gru2(f, bd, BB);
  }

  // ---------------- encoder layer 1 (chunked hoisted x-proj) ------------------
  for (int ch = 0; ch < 8; ++ch) {
    int t0 = ch * 16;
    // fwd chunk: proj of y0[t0 + tl], dir-0 weights
    gemm_chunk_k<<<dim3(128, 24), 256, 0, stream>>>(
        y0b + (size_t)t0 * 1024, 1024, wb_e1_Wih, enc1_bih, gxF);
    // bwd chunk: step s = t0+tl uses source tr = 127 - s, dir-1 weights
    gemm_chunk_k<<<dim3(128, 24), 256, 0, stream>>>(
        y0b + (size_t)(127 - t0) * 1024, -1024, wb_e1_Wih + 1572864, enc1_bih + GG, gxB);
    for (int tl = 0; tl < 16; ++tl) {
      int t = t0 + tl;
      GruP f = {};
      f.hz = (t == 0);
      f.h_prev = h1f_pp[(t + 1) & 1]; f.hs = 512;
      f.Whh = wb_e1_Whh; f.bhh = enc1_bhh;
      f.gxb = gxF; f.gxros = tl * 256;
      f.h_out = h1f_pp[t & 1]; f.os = 512;
      GruP bd = {};
      bd.hz = (t == 0);
      bd.h_prev = h1b_pp[(t + 1) & 1]; bd.hs = 512;
      bd.Whh = wb_e1_Whh + 786432; bd.bhh = enc1_bhh + GG;
      bd.gxb = gxB; bd.gxros = tl * 256;
      bd.h_out = h1b_pp[t & 1]; bd.os = 512;
      gru2(f, bd, BB);
    }
  }

  // ---------------- latent ----------------------------------------------------
  gather_hidden_k<<<2048, 256, 0, stream>>>(y0b, h1f_pp[1], h1b_pp[1], hidden);
  gemmM(hidden, 2048, W_mu, 2048, b_mu, mu_f, 512, BB, 512, 2048);
  gemmM(hidden, 2048, W_lv, 2048, b_lv, lv_f, 512, BB, 512, 2048);
  z_k<<<512, 256, 0, stream>>>(mu_f, lv_f, eps, zz, out_mu, out_lv);
  gemmM(zz, 512, W_ci, 512, b_ci, ci, 96, BB, 96, 512);
  gemmM(zz, 512, W_ch, 512, b_ch, chv, 512, BB, 512, 512);
  gemmM(ci, 96, con0_Wih, 96, con0_bih, gx_c0, GG, BB, GG, 96);

  // ---------------- conductor (y0b region now dead) ---------------------------
  for (int bar = 0; bar < NBB; ++bar) {
    GruP c0 = {};
    c0.h_prev = (bar == 0) ? chv : h0c + (size_t)(bar - 1) * 131072; c0.hs = 512;
    c0.gxf = gx_c0;
    c0.Whh = wb_c0_Whh; c0.bhh = con0_bhh;
    c0.h_out = h0c + (size_t)bar * 131072; c0.os = 512;
    gru1(c0, BB);
    GruP c1 = {};
    c1.h_prev = (bar == 0) ? chv : h1c + (size_t)(bar - 1) * 131072; c1.hs = 512;
    c1.x0f = h0c + (size_t)bar * 131072; c1.x0s = 512;
    c1.W0 = wb_c1_Wih; c1.w0ld = 512; c1.K0 = 512;
    c1.Whh = wb_c1_Whh; c1.bih = con1_bih; c1.bhh = con1_bhh;
    c1.h_out = h1c + (size_t)bar * 131072; c1.os = 512;
    gru1(c1, BB);
  }

  // ---------------- decoder: 8192 rows, 4 steps -------------------------------
  const int R = NBB * BB;
  for (int s = 0; s < CPBB; ++s) {
    GruP d0 = {};
    d0.h_prev = (s == 0) ? h0c : d0p[(s - 1) & 1]; d0.hs = 512;
    d0.x0f = h1c; d0.x0s = 512; d0.W0 = wb_d0_Wih; d0.w0ld = 608; d0.K0 = 512;
    d0.x1f = in; d0.x1sp = s; d0.W1 = wb_d0_Wih + 512; d0.w1ld = 608; d0.K1 = 96;
    d0.Whh = wb_d0_Whh; d0.bih = dec0_bih; d0.bhh = dec0_bhh;
    d0.h_out = d0p[s & 1]; d0.os = 512;
    gru1(d0, R);
    GruP d1 = {};
    d1.h_prev = (s == 0) ? h1c : d1p[(s - 1) & 1]; d1.hs = 512;
    d1.x0f = d0p[s & 1]; d1.x0s = 512; d1.W0 = wb_d1_Wih; d1.w0ld = 512; d1.K0 = 512;
    d1.Whh = wb_d1_Whh; d1.bih = dec1_bih; d1.bhh = dec1_bhh;
    d1.h_out = d1p[s & 1]; d1.os = 512;
    gru1(d1, R);
    gemmM(d1p[s & 1], 512, W_out, 512, b_out, logits_q + (size_t)s * 96, 384, R, 96, 512);
  }

  // ---------------- softmax + echo --------------------------------------------
  softmax_k<<<NBB * BB * CPBB, 64, 0, stream>>>(logits_q, out_sm, out_ls);
  echo_k<<<12288, 256, 0, stream>>>(in, out_ec);
}